// Round 3
// baseline (663.974 us; speedup 1.0000x reference)
//
#include <hip/hip_runtime.h>
#include <hip/hip_bf16.h>

typedef __attribute__((ext_vector_type(8))) short short8;
typedef __attribute__((ext_vector_type(4))) float f32x4;

#define DI __device__ __forceinline__

DI unsigned short f2b(float f){
  union{float ff; unsigned u;} v; v.ff=f;
  unsigned r = v.u;
  r += 0x7fffu + ((r>>16)&1u);   // RNE
  return (unsigned short)(r>>16);
}
DI float b2f(unsigned short h){
  union{unsigned u; float ff;} v; v.u = ((unsigned)h)<<16; return v.ff;
}

DI float dot8(short8 wv, const float* x){
  float s = 0.f;
  #pragma unroll
  for (int i=0;i<8;++i) s += b2f((unsigned short)wv[i]) * x[i];
  return s;
}

// block-wide (256 thr) sum of two values
DI void bred2(float& a, float& b, float* red){
  #pragma unroll
  for (int o=32;o>0;o>>=1){ a += __shfl_xor(a,o); b += __shfl_xor(b,o); }
  int wid = threadIdx.x>>6;
  __syncthreads();
  if ((threadIdx.x&63)==0){ red[wid*2]=a; red[wid*2+1]=b; }
  __syncthreads();
  a = red[0]+red[2]+red[4]+red[6];
  b = red[1]+red[3]+red[5]+red[7];
}

// ---------------- k0: weight bf16 conversion (blocks 0..703) + slot init/q0 (blocks 704..959) ----
__global__ void k0(const float* __restrict__ Wk, const float* __restrict__ Wv,
                   const float* __restrict__ Wih, const float* __restrict__ Whh,
                   const float* __restrict__ W1, const float* __restrict__ W2,
                   const float* __restrict__ Wq,
                   unsigned short* Wkvb, unsigned short* Wihb, unsigned short* Whhb,
                   unsigned short* W1b, unsigned short* W2b, unsigned short* Wqb,
                   const float* __restrict__ noise, const float* __restrict__ mu,
                   const float* __restrict__ ls, const float* __restrict__ lnsg,
                   const float* __restrict__ lnsb,
                   float* slots, unsigned short* qbuf){
  __shared__ __align__(16) float sn[256];
  __shared__ float red[8];
  int t = threadIdx.x, blk = blockIdx.x;
  if (blk < 704){
    int j = blk*1024 + t*4;
    const float* sp; unsigned short* dp;
    if (j < 65536){ sp=Wk+j; dp=Wkvb+j; }
    else if (j < 131072){ sp=Wv+(j-65536); dp=Wkvb+j; }
    else if (j < 327680){ sp=Wih+(j-131072); dp=Wihb+(j-131072); }
    else if (j < 524288){ sp=Whh+(j-327680); dp=Whhb+(j-327680); }
    else if (j < 589824){ sp=W1+(j-524288); dp=W1b+(j-524288); }
    else if (j < 655360){ sp=W2+(j-589824); dp=W2b+(j-589824); }
    else { sp=Wq+(j-655360); dp=Wqb+(j-655360); }
    float4 v = *(const float4*)sp;
    dp[0]=f2b(v.x); dp[1]=f2b(v.y); dp[2]=f2b(v.z); dp[3]=f2b(v.w);
  } else {
    int r = blk - 704;
    int b = r>>3, k = r&7;
    float val = mu[t] + __expf(ls[t]) * noise[r*256 + t];
    slots[r*256 + t] = val;
    qbuf[(b*16 + 8 + k)*256 + t] = 0;      // zero q pad rows (slots 8..15)
    float sa = val, sb = val*val;
    bred2(sa, sb, red);
    float m = sa*(1.f/256.f);
    float var = sb*(1.f/256.f) - m*m;
    float inv = rsqrtf(fmaxf(var, 0.f) + 1e-5f);
    sn[t] = (val - m)*inv*lnsg[t] + lnsb[t];
    __syncthreads();
    const float* wr = Wq + (size_t)t*256;
    float acc = 0.f;
    #pragma unroll 8
    for (int c=0;c<64;++c){
      float4 wv = *(const float4*)(wr + c*4);
      acc += wv.x*sn[c*4] + wv.y*sn[c*4+1] + wv.z*sn[c*4+2] + wv.w*sn[c*4+3];
    }
    qbuf[(b*16 + k)*256 + t] = f2b(acc * 0.0625f);   // SCALE folded in
  }
}

// ---------------- k1: LN(embeddings) + keys/values projection ----------------
// grid 2048 (64 n-rows each), 256 thr, 4 waves. Wave w: mh=w&1 (rows 32mh..+31),
// ch=w>>1 (chunks: ch=0 -> keys cols 0..255; ch=1 -> values cols 0..255 -> vT).
// A-frags read from LDS ONCE into regs; ONE barrier total; wave-private epilogue LDS.
__global__ __launch_bounds__(256) void k1(const float* __restrict__ emb,
                                          const unsigned short* __restrict__ Wkvb,
                                          const float* __restrict__ lng, const float* __restrict__ lnb,
                                          unsigned short* __restrict__ keys, unsigned short* __restrict__ vT){
  __shared__ __align__(16) char xl[32768];        // LN(x) [64][256] bf16, 16B-chunk XOR swizzle
  __shared__ __align__(16) char st[4][1536];      // wave-private epilogue scratch
  int t = threadIdx.x, blk = blockIdx.x;
  int w = t>>6, l = t&63, l15 = l&15, lg = (l>>4)&3;
  int mh = w&1, ch = w>>1;
  {
    int r = t>>2, q4 = t&3;
    const float* erow = emb + ((size_t)blk*64 + r)*256 + q4*64;
    float v[64];
    float sum=0.f, sq=0.f;
    #pragma unroll
    for (int jj=0;jj<16;++jj){
      float4 f = *(const float4*)(erow + jj*4);
      v[jj*4+0]=f.x; v[jj*4+1]=f.y; v[jj*4+2]=f.z; v[jj*4+3]=f.w;
      sum += f.x+f.y+f.z+f.w;
      sq  += f.x*f.x + f.y*f.y + f.z*f.z + f.w*f.w;
    }
    sum += __shfl_xor(sum,1); sq += __shfl_xor(sq,1);
    sum += __shfl_xor(sum,2); sq += __shfl_xor(sq,2);
    float m = sum*(1.f/256.f);
    float var = sq*(1.f/256.f) - m*m;
    float inv = rsqrtf(fmaxf(var,0.f) + 1e-5f);
    int r7 = r&7;
    #pragma unroll
    for (int jp=0;jp<8;++jp){
      int d0 = q4*64 + jp*8;
      float4 g0 = *(const float4*)(lng + d0); float4 g1 = *(const float4*)(lng + d0 + 4);
      float4 b0 = *(const float4*)(lnb + d0); float4 b1 = *(const float4*)(lnb + d0 + 4);
      short8 pk;
      pk[0]=(short)f2b((v[jp*8+0]-m)*inv*g0.x + b0.x);
      pk[1]=(short)f2b((v[jp*8+1]-m)*inv*g0.y + b0.y);
      pk[2]=(short)f2b((v[jp*8+2]-m)*inv*g0.z + b0.z);
      pk[3]=(short)f2b((v[jp*8+3]-m)*inv*g0.w + b0.w);
      pk[4]=(short)f2b((v[jp*8+4]-m)*inv*g1.x + b1.x);
      pk[5]=(short)f2b((v[jp*8+5]-m)*inv*g1.y + b1.y);
      pk[6]=(short)f2b((v[jp*8+6]-m)*inv*g1.z + b1.z);
      pk[7]=(short)f2b((v[jp*8+7]-m)*inv*g1.w + b1.w);
      int c16 = q4*8 + jp;
      *(short8*)(xl + r*512 + ((c16 ^ r7)<<4)) = pk;
    }
  }
  __syncthreads();   // the only barrier
  // A-fragments into registers (chunk-invariant)
  short8 af0[8], af1[8];
  #pragma unroll
  for (int s=0;s<8;++s){
    int r0 = 32*mh + l15, r1 = 32*mh + 16 + l15;
    af0[s] = *(const short8*)(xl + r0*512 + (((lg + s*4) ^ (r0&7))<<4));
    af1[s] = *(const short8*)(xl + r1*512 + (((lg + s*4) ^ (r1&7))<<4));
  }
  f32x4 z4 = {0.f,0.f,0.f,0.f};
  size_t bb = blk>>6;
  int n0b = (blk&63)*64;
  char* myst = st[w];
  if (ch == 0){
    // keys path: region [32 rows][24 shorts] (32B data + 16B pad per row)
    unsigned short* kst = (unsigned short*)myst;
    #pragma unroll 4
    for (int step=0; step<16; ++step){
      int c = step>>2, ct = step&3;
      const unsigned short* wp = Wkvb + (size_t)(c*64 + ct*16 + l15)*256 + lg*8;
      short8 bf[8];
      #pragma unroll
      for (int s=0;s<8;++s) bf[s] = *(const short8*)(wp + s*32);
      f32x4 a0 = z4, a1 = z4;
      #pragma unroll
      for (int s=0;s<8;++s){
        a0 = __builtin_amdgcn_mfma_f32_16x16x32_bf16(af0[s], bf[s], a0, 0,0,0);
        a1 = __builtin_amdgcn_mfma_f32_16x16x32_bf16(af1[s], bf[s], a1, 0,0,0);
      }
      #pragma unroll
      for (int j=0;j<4;++j){
        kst[(lg*4+j)*24 + l15]      = f2b(a0[j]);
        kst[(16+lg*4+j)*24 + l15]   = f2b(a1[j]);
      }
      int r = l>>1, hf = l&1;
      int4 dv = *(const int4*)(kst + r*24 + hf*8);
      size_t off = ((size_t)blk*64 + 32*mh + r)*256 + c*64 + ct*16 + hf*8;
      *(int4*)(keys + off) = dv;
    }
  } else {
    // values path: region [16 cols(dout)][40 shorts] (32 n + 8 pad)
    unsigned short* vst = (unsigned short*)myst;
    #pragma unroll 4
    for (int step=0; step<16; ++step){
      int c = step>>2, ct = step&3;
      const unsigned short* wp = Wkvb + (size_t)((c+4)*64 + ct*16 + l15)*256 + lg*8;
      short8 bf[8];
      #pragma unroll
      for (int s=0;s<8;++s) bf[s] = *(const short8*)(wp + s*32);
      f32x4 a0 = z4, a1 = z4;
      #pragma unroll
      for (int s=0;s<8;++s){
        a0 = __builtin_amdgcn_mfma_f32_16x16x32_bf16(af0[s], bf[s], a0, 0,0,0);
        a1 = __builtin_amdgcn_mfma_f32_16x16x32_bf16(af1[s], bf[s], a1, 0,0,0);
      }
      ushort4 p0; p0.x=f2b(a0[0]); p0.y=f2b(a0[1]); p0.z=f2b(a0[2]); p0.w=f2b(a0[3]);
      ushort4 p1; p1.x=f2b(a1[0]); p1.y=f2b(a1[1]); p1.z=f2b(a1[2]); p1.w=f2b(a1[3]);
      *(ushort4*)(vst + l15*40 + lg*4)      = p0;
      *(ushort4*)(vst + l15*40 + 16 + lg*4) = p1;
      int dl = l>>2, seg = l&3;
      int4 dv = *(const int4*)(vst + dl*40 + seg*8);
      size_t off = (bb*256 + (size_t)(c*64 + ct*16 + dl))*4096 + n0b + 32*mh + seg*8;
      *(int4*)(vT + off) = dv;
    }
  }
}

// ---------------- k3: dots -> softmax(K) -> partial S / unnormalized updates ----------------
// grid 2048 = 32 b x 64 n-blocks of 64 n; 256 thr (4 waves). All streamed loads issued
// up-front; ONE barrier (attn exchange). Partial sums per block (no atomics).
__global__ __launch_bounds__(256) void k3(const unsigned short* __restrict__ keys,
                                          const unsigned short* __restrict__ vT,
                                          const unsigned short* __restrict__ qbuf,
                                          float* __restrict__ Upart, float* __restrict__ Spart,
                                          float* __restrict__ outA, int last){
  __shared__ __align__(16) char al[2048];   // attn [16 slots][64 n] bf16, row-XOR swizzled
  __shared__ float sS[4][8];
  int t = threadIdx.x, w = t>>6, l = t&63;
  int l15 = l&15, lg = (l>>4)&3;
  int b = blockIdx.x >> 6;
  int n0 = (blockIdx.x & 63) << 6;
  if (t >= 64 && t < 128){ int4 zz = {0,0,0,0}; ((int4*)al)[t] = zz; }  // zero pad rows 8..15
  // streamed loads first (HBM): keys fragments then vT fragments
  const unsigned short* kb = keys + ((size_t)b*4096 + n0 + 16*w + l15)*256 + lg*8;
  short8 kf[8];
  #pragma unroll
  for (int s=0;s<8;++s) kf[s] = *(const short8*)(kb + s*32);
  const unsigned short* vb = vT + (size_t)b*1048576 + n0 + lg*8;
  short8 vf[2][4];
  #pragma unroll
  for (int s2=0;s2<2;++s2)
    #pragma unroll
    for (int dt=0;dt<4;++dt)
      vf[s2][dt] = *(const short8*)(vb + (size_t)((4*w+dt)*16 + l15)*4096 + s2*32);
  // queries (L2-hot)
  short8 qf[8];
  const unsigned short* qb = qbuf + (size_t)b*4096 + l15*256 + lg*8;
  #pragma unroll
  for (int s=0;s<8;++s) qf[s] = *(const short8*)(qb + s*32);
  f32x4 z4 = {0.f,0.f,0.f,0.f};
  f32x4 dacc = z4;
  #pragma unroll
  for (int s=0;s<8;++s)
    dacc = __builtin_amdgcn_mfma_f32_16x16x32_bf16(qf[s], kf[s], dacc, 0,0,0);
  // softmax over 8 slots per n (slots 0-3 lanes 0-15, 4-7 lanes 16-31)
  float d0=dacc[0], d1=dacc[1], d2=dacc[2], d3=dacc[3];
  float mx = fmaxf(fmaxf(d0,d1), fmaxf(d2,d3));
  mx = fmaxf(mx, __shfl_xor(mx,16));
  float e0=__expf(d0-mx), e1=__expf(d1-mx), e2=__expf(d2-mx), e3=__expf(d3-mx);
  float se = e0+e1+e2+e3;
  se += __shfl_xor(se,16);
  float inv = 1.f/se;
  float a0=e0*inv+1e-8f, a1=e1*inv+1e-8f, a2=e2*inv+1e-8f, a3=e3*inv+1e-8f;
  float sp[4] = {a0,a1,a2,a3};
  if (l < 32){
    int rr = lg<<2;
    int nc2 = (w*16 + l15)*2;
    *(unsigned short*)(al + (rr+0)*128 + (nc2 ^ ((rr+0)<<4))) = f2b(a0);
    *(unsigned short*)(al + (rr+1)*128 + (nc2 ^ ((rr+1)<<4))) = f2b(a1);
    *(unsigned short*)(al + (rr+2)*128 + (nc2 ^ ((rr+2)<<4))) = f2b(a2);
    *(unsigned short*)(al + (rr+3)*128 + (nc2 ^ ((rr+3)<<4))) = f2b(a3);
    if (last){
      size_t o = ((size_t)b*8 + rr)*4096 + n0 + w*16 + l15;
      outA[o] = a0; outA[o+4096]=a1; outA[o+8192]=a2; outA[o+12288]=a3;
    }
  }
  __syncthreads();   // the only barrier
  // updates: A = attn [16 x 64n] from LDS, B = vT fragments (already in regs)
  f32x4 upd[4] = {z4,z4,z4,z4};
  #pragma unroll
  for (int s2=0;s2<2;++s2){
    int ck = (lg<<4) + (s2<<6);
    short8 afr = *(const short8*)(al + l15*128 + (ck ^ ((l15&7)<<4)));
    #pragma unroll
    for (int dt=0;dt<4;++dt)
      upd[dt] = __builtin_amdgcn_mfma_f32_16x16x32_bf16(afr, vf[s2][dt], upd[dt], 0,0,0);
  }
  #pragma unroll
  for (int j=0;j<4;++j){
    sp[j] += __shfl_xor(sp[j],1);
    sp[j] += __shfl_xor(sp[j],2);
    sp[j] += __shfl_xor(sp[j],4);
    sp[j] += __shfl_xor(sp[j],8);
  }
  if (l15==0 && l<32){
    int rr = lg<<2;
    sS[w][rr+0]=sp[0]; sS[w][rr+1]=sp[1]; sS[w][rr+2]=sp[2]; sS[w][rr+3]=sp[3];
  }
  __syncthreads();
  if (t < 8) Spart[(size_t)blockIdx.x*8 + t] = sS[0][t]+sS[1][t]+sS[2][t]+sS[3][t];
  if (l < 32){
    int rr = lg<<2;
    float* up = Upart + (size_t)blockIdx.x*2048;
    #pragma unroll
    for (int dt=0;dt<4;++dt){
      int d = (4*w+dt)*16 + l15;
      up[(rr+0)*256 + d] = upd[dt][0];
      up[(rr+1)*256 + d] = upd[dt][1];
      up[(rr+2)*256 + d] = upd[dt][2];
      up[(rr+3)*256 + d] = upd[dt][3];
    }
  }
}

// ---------------- k4: partial-reduce + GRU + residual MLP + next queries ----------------
// grid 256 (one block per slot-row), 256 thr (t = d index and out index)
__global__ void k4(const float* __restrict__ Upart, const float* __restrict__ Spart,
                   float* __restrict__ slots,
                   const float* __restrict__ bih, const float* __restrict__ bhh,
                   const unsigned short* __restrict__ Wihb, const unsigned short* __restrict__ Whhb,
                   const unsigned short* __restrict__ W1b, const unsigned short* __restrict__ W2b,
                   const unsigned short* __restrict__ Wqb,
                   const float* __restrict__ pb1, const float* __restrict__ pb2,
                   const float* __restrict__ lnfg, const float* __restrict__ lnfb,
                   const float* __restrict__ lnsg, const float* __restrict__ lnsb,
                   unsigned short* __restrict__ qbuf, float* __restrict__ outS, int last){
  __shared__ __align__(16) float uh[512];
  __shared__ __align__(16) float yl[256];
  __shared__ __align__(16) float y1l[256];
  __shared__ float red[8];
  int r = blockIdx.x, t = threadIdx.x;
  int b = r>>3, k = r&7;
  float Sr = 0.f, u = 0.f;
  #pragma unroll 8
  for (int nb=0;nb<64;++nb){
    size_t bn = (size_t)(b*64 + nb);
    Sr += Spart[bn*8 + k];
    u  += Upart[bn*2048 + k*256 + t];
  }
  u /= Sr;
  float h = slots[r*256 + t];
  uh[t] = u; uh[256 + t] = h;
  __syncthreads();
  float gir = bih[t], giz = bih[256+t], gin = bih[512+t];
  float ghr = bhh[t], ghz = bhh[256+t], ghn = bhh[512+t];
  {
    const unsigned short* p0 = Wihb + (size_t)t*256;
    const unsigned short* p1 = Wihb + (size_t)(256+t)*256;
    const unsigned short* p2 = Wihb + (size_t)(512+t)*256;
    const unsigned short* p3 = Whhb + (size_t)t*256;
    const unsigned short* p4 = Whhb + (size_t)(256+t)*256;
    const unsigned short* p5 = Whhb + (size_t)(512+t)*256;
    #pragma unroll 2
    for (int c=0;c<32;++c){
      const float* ux = uh + c*8;
      const float* hx = uh + 256 + c*8;
      gir += dot8(*(const short8*)(p0 + c*8), ux);
      giz += dot8(*(const short8*)(p1 + c*8), ux);
      gin += dot8(*(const short8*)(p2 + c*8), ux);
      ghr += dot8(*(const short8*)(p3 + c*8), hx);
      ghz += dot8(*(const short8*)(p4 + c*8), hx);
      ghn += dot8(*(const short8*)(p5 + c*8), hx);
    }
  }
  float rg = 1.f/(1.f+__expf(-(gir+ghr)));
  float zz = 1.f/(1.f+__expf(-(giz+ghz)));
  float ng = tanhf(gin + rg*ghn);
  float s1 = (1.f-zz)*ng + zz*h;
  // LN_ff
  float sa = s1, sb = s1*s1;
  bred2(sa, sb, red);
  float m = sa*(1.f/256.f);
  float var = sb*(1.f/256.f) - m*m;
  float yv = (s1-m)*rsqrtf(fmaxf(var,0.f)+1e-5f)*lnfg[t] + lnfb[t];
  yl[t] = yv;
  __syncthreads();
  float a1 = pb1[t];
  const unsigned short* q1 = W1b + (size_t)t*256;
  #pragma unroll 2
  for (int c=0;c<32;++c) a1 += dot8(*(const short8*)(q1 + c*8), yl + c*8);
  float y1 = (a1 > 0.f) ? a1 : 0.01f*a1;
  y1l[t] = y1;
  __syncthreads();
  float a2 = pb2[t];
  const unsigned short* q2 = W2b + (size_t)t*256;
  #pragma unroll 2
  for (int c=0;c<32;++c) a2 += dot8(*(const short8*)(q2 + c*8), y1l + c*8);
  float s2v = s1 + a2;
  slots[r*256 + t] = s2v;
  if (last){
    outS[r*256 + t] = s2v;
  } else {
    float ta = s2v, tb = s2v*s2v;
    bred2(ta, tb, red);
    float m2 = ta*(1.f/256.f);
    float v2 = tb*(1.f/256.f) - m2*m2;
    float snv = (s2v - m2)*rsqrtf(fmaxf(v2,0.f)+1e-5f)*lnsg[t] + lnsb[t];
    __syncthreads();
    yl[t] = snv;
    __syncthreads();
    float aq = 0.f;
    const unsigned short* q3 = Wqb + (size_t)t*256;
    #pragma unroll 2
    for (int c=0;c<32;++c) aq += dot8(*(const short8*)(q3 + c*8), yl + c*8);
    qbuf[(b*16 + k)*256 + t] = f2b(aq * 0.0625f);
  }
}

extern "C" void kernel_launch(void* const* d_in, const int* in_sizes, int n_in,
                              void* d_out, int out_size, void* d_ws, size_t ws_size,
                              hipStream_t stream) {
  (void)in_sizes; (void)n_in; (void)out_size; (void)ws_size;
  const float* emb  = (const float*)d_in[0];
  const float* noise= (const float*)d_in[1];
  const float* mu   = (const float*)d_in[2];
  const float* ls   = (const float*)d_in[3];
  const float* Wq   = (const float*)d_in[4];
  const float* Wk   = (const float*)d_in[5];
  const float* Wv   = (const float*)d_in[6];
  const float* Wih  = (const float*)d_in[7];
  const float* Whh  = (const float*)d_in[8];
  const float* bih  = (const float*)d_in[9];
  const float* bhh  = (const float*)d_in[10];
  const float* W1   = (const float*)d_in[11];
  const float* b1   = (const float*)d_in[12];
  const float* W2   = (const float*)d_in[13];
  const float* b2   = (const float*)d_in[14];
  const float* lnig = (const float*)d_in[15];
  const float* lnib = (const float*)d_in[16];
  const float* lnsg = (const float*)d_in[17];
  const float* lnsb = (const float*)d_in[18];
  const float* lnfg = (const float*)d_in[19];
  const float* lnfb = (const float*)d_in[20];

  unsigned short* keys = (unsigned short*)d_ws;      // 33554432
  unsigned short* vT   = keys + 33554432;            // 33554432
  unsigned short* Wkvb = vT + 33554432;              // 131072
  unsigned short* Wihb = Wkvb + 131072;              // 196608
  unsigned short* Whhb = Wihb + 196608;              // 196608
  unsigned short* W1b  = Whhb + 196608;              // 65536
  unsigned short* W2b  = W1b + 65536;                // 65536
  unsigned short* Wqb  = W2b + 65536;                // 65536
  unsigned short* qbuf = Wqb + 65536;                // 131072
  float* slots = (float*)(qbuf + 131072);            // 65536 f32
  float* Upart = slots + 65536;                      // 4194304 f32 (2048 blocks x 8 x 256)
  float* Spart = Upart + 4194304;                    // 16384 f32
  float* outS = (float*)d_out;
  float* outA = outS + 65536;

  k0<<<960, 256, 0, stream>>>(Wk, Wv, Wih, Whh, W1, W2, Wq,
                              Wkvb, Wihb, Whhb, W1b, W2b, Wqb,
                              noise, mu, ls, lnsg, lnsb, slots, qbuf);
  k1<<<2048, 256, 0, stream>>>(emb, Wkvb, lnig, lnib, keys, vT);
  for (int it=0; it<3; ++it){
    int lastf = (it==2) ? 1 : 0;
    k3<<<2048, 256, 0, stream>>>(keys, vT, qbuf, Upart, Spart, outA, lastf);
    k4<<<256, 256, 0, stream>>>(Upart, Spart, slots, bih, bhh, Wihb, Whhb, W1b, W2b, Wqb,
                                b1, b2, lnfg, lnfb, lnsg, lnsb, qbuf, outS, lastf);
  }
}